// Round 1
// baseline (1777.045 us; speedup 1.0000x reference)
//
#include <hip/hip_runtime.h>
#include <math.h>

#define HH 768
#define NHEADS 12
#define HDIM 64
#define SEQ 2048
#define NB 2
// M_total = NB*SEQ = 4096

// ---------------------------------------------------------------------------
// GEMM (BT form): C[m,n] = sum_k A[m,k] * W[n,k] + bias[n]
// Variant 1: writes out in [B, NH, S, HD] layout (for Q/K/V).
// ---------------------------------------------------------------------------
__global__ __launch_bounds__(256)
void gemm_qkv_kernel(const float* __restrict__ X, const float* __restrict__ W,
                     const float* __restrict__ bias, float* __restrict__ out)
{
    __shared__ float As[64][20];
    __shared__ float Ws[64][20];
    const int tid = threadIdx.x;
    const int n0 = blockIdx.x * 64;
    const int m0 = blockIdx.y * 64;
    const int ty = tid >> 4;          // 0..15
    const int tx = tid & 15;          // 0..15
    const int lr = tid >> 2;          // 0..63 (row for cooperative load)
    const int lc = (tid & 3) << 2;    // 0,4,8,12
    float acc[4][4] = {};

    for (int k0 = 0; k0 < HH; k0 += 16) {
        float4 av = *(const float4*)(X + (size_t)(m0 + lr) * HH + k0 + lc);
        float4 wv = *(const float4*)(W + (size_t)(n0 + lr) * HH + k0 + lc);
        *(float4*)&As[lr][lc] = av;
        *(float4*)&Ws[lr][lc] = wv;
        __syncthreads();
        #pragma unroll
        for (int kk = 0; kk < 16; kk++) {
            float a[4], b[4];
            #pragma unroll
            for (int i = 0; i < 4; i++) a[i] = As[ty*4+i][kk];
            #pragma unroll
            for (int j = 0; j < 4; j++) b[j] = Ws[tx*4+j][kk];
            #pragma unroll
            for (int i = 0; i < 4; i++)
                #pragma unroll
                for (int j = 0; j < 4; j++)
                    acc[i][j] = fmaf(a[i], b[j], acc[i][j]);
        }
        __syncthreads();
    }

    #pragma unroll
    for (int i = 0; i < 4; i++) {
        const int gm = m0 + ty*4 + i;      // 0..4095
        const int bb = gm >> 11;           // batch
        const int s  = gm & 2047;          // seq pos
        #pragma unroll
        for (int j = 0; j < 4; j++) {
            const int n = n0 + tx*4 + j;   // 0..767
            const int h = n >> 6;
            const int d = n & 63;
            out[((size_t)((bb*NHEADS + h) * SEQ) + s) * HDIM + d] = acc[i][j] + bias[n];
        }
    }
}

// ---------------------------------------------------------------------------
// Variant 2: out-projection. y[m,n] = sum_k CTX[m,k]*Wo[n,k] + bo[n] + X[m,n]
// Writes linear [4096, 768] into d_out.
// ---------------------------------------------------------------------------
__global__ __launch_bounds__(256)
void gemm_proj_kernel(const float* __restrict__ CTX, const float* __restrict__ W,
                      const float* __restrict__ bias, const float* __restrict__ X,
                      float* __restrict__ out)
{
    __shared__ float As[64][20];
    __shared__ float Ws[64][20];
    const int tid = threadIdx.x;
    const int n0 = blockIdx.x * 64;
    const int m0 = blockIdx.y * 64;
    const int ty = tid >> 4;
    const int tx = tid & 15;
    const int lr = tid >> 2;
    const int lc = (tid & 3) << 2;
    float acc[4][4] = {};

    for (int k0 = 0; k0 < HH; k0 += 16) {
        float4 av = *(const float4*)(CTX + (size_t)(m0 + lr) * HH + k0 + lc);
        float4 wv = *(const float4*)(W   + (size_t)(n0 + lr) * HH + k0 + lc);
        *(float4*)&As[lr][lc] = av;
        *(float4*)&Ws[lr][lc] = wv;
        __syncthreads();
        #pragma unroll
        for (int kk = 0; kk < 16; kk++) {
            float a[4], b[4];
            #pragma unroll
            for (int i = 0; i < 4; i++) a[i] = As[ty*4+i][kk];
            #pragma unroll
            for (int j = 0; j < 4; j++) b[j] = Ws[tx*4+j][kk];
            #pragma unroll
            for (int i = 0; i < 4; i++)
                #pragma unroll
                for (int j = 0; j < 4; j++)
                    acc[i][j] = fmaf(a[i], b[j], acc[i][j]);
        }
        __syncthreads();
    }

    #pragma unroll
    for (int i = 0; i < 4; i++) {
        const int gm = m0 + ty*4 + i;
        #pragma unroll
        for (int j = 0; j < 4; j++) {
            const int n = n0 + tx*4 + j;
            out[(size_t)gm * HH + n] = acc[i][j] + bias[n] + X[(size_t)gm * HH + n];
        }
    }
}

// ---------------------------------------------------------------------------
// Flash attention, fp32. One block = (b, h, 32 query rows). K/V tiles of 32.
// Q/K/V layout: [B, NH, S, HD]. Output CTX layout: [B, S, H] (heads merged).
// ---------------------------------------------------------------------------
__global__ __launch_bounds__(256)
void attn_kernel(const float* __restrict__ Q, const float* __restrict__ K,
                 const float* __restrict__ V, const float* __restrict__ mask,
                 float* __restrict__ CTX)
{
    const int qt = blockIdx.x;   // 0..63
    const int h  = blockIdx.y;   // 0..11
    const int b  = blockIdx.z;   // 0..1
    const size_t base = ((size_t)(b * NHEADS + h)) * SEQ * HDIM;

    __shared__ float Qs[32][68];
    __shared__ float Ks[32][68];
    __shared__ float Vs[32][68];
    __shared__ float Ps[32][33];
    __shared__ float Ms[32];
    __shared__ float rowm[32], rowl[32], rowa[32];

    const int tid = threadIdx.x;
    const int qr  = tid >> 3;          // 0..31 (row this thread accumulates)
    const int d8  = (tid & 7) << 3;    // 0,8,...,56
    const int lr  = tid >> 3;          // load row 0..31
    const int lc  = (tid & 7) << 3;    // load col 0,8,...,56

    float acc[8] = {0,0,0,0,0,0,0,0};

    {   // load Q tile once
        const float* src = Q + base + (size_t)(qt*32 + lr) * HDIM + lc;
        *(float4*)&Qs[lr][lc]   = *(const float4*)(src);
        *(float4*)&Qs[lr][lc+4] = *(const float4*)(src + 4);
    }
    if (tid < 32) { rowm[tid] = -1e30f; rowl[tid] = 0.0f; }
    __syncthreads();

    for (int kt = 0; kt < SEQ/32; kt++) {
        {   // stage K, V tiles + mask terms
            const float* ksrc = K + base + (size_t)(kt*32 + lr) * HDIM + lc;
            const float* vsrc = V + base + (size_t)(kt*32 + lr) * HDIM + lc;
            *(float4*)&Ks[lr][lc]   = *(const float4*)(ksrc);
            *(float4*)&Ks[lr][lc+4] = *(const float4*)(ksrc + 4);
            *(float4*)&Vs[lr][lc]   = *(const float4*)(vsrc);
            *(float4*)&Vs[lr][lc+4] = *(const float4*)(vsrc + 4);
            if (tid < 32) Ms[tid] = (1.0f - mask[b*SEQ + kt*32 + tid]) * -10000.0f;
        }
        __syncthreads();

        {   // scores: thread computes S[sr][sc..sc+3]
            const int sr = tid >> 3;
            const int sc = (tid & 7) << 2;
            float s0 = 0.f, s1 = 0.f, s2 = 0.f, s3 = 0.f;
            #pragma unroll
            for (int d = 0; d < HDIM; d += 4) {
                float4 q4 = *(float4*)&Qs[sr][d];
                float4 k0 = *(float4*)&Ks[sc+0][d];
                float4 k1 = *(float4*)&Ks[sc+1][d];
                float4 k2 = *(float4*)&Ks[sc+2][d];
                float4 k3 = *(float4*)&Ks[sc+3][d];
                s0 += q4.x*k0.x + q4.y*k0.y + q4.z*k0.z + q4.w*k0.w;
                s1 += q4.x*k1.x + q4.y*k1.y + q4.z*k1.z + q4.w*k1.w;
                s2 += q4.x*k2.x + q4.y*k2.y + q4.z*k2.z + q4.w*k2.w;
                s3 += q4.x*k3.x + q4.y*k3.y + q4.z*k3.z + q4.w*k3.w;
            }
            Ps[sr][sc+0] = s0 * 0.125f + Ms[sc+0];
            Ps[sr][sc+1] = s1 * 0.125f + Ms[sc+1];
            Ps[sr][sc+2] = s2 * 0.125f + Ms[sc+2];
            Ps[sr][sc+3] = s3 * 0.125f + Ms[sc+3];
        }
        __syncthreads();

        if (tid < 32) {  // online softmax, one thread per row (baseline)
            const int r = tid;
            float mo = rowm[r];
            float mn = mo;
            #pragma unroll 8
            for (int j = 0; j < 32; j++) mn = fmaxf(mn, Ps[r][j]);
            float lsum = 0.f;
            #pragma unroll 8
            for (int j = 0; j < 32; j++) {
                float p = __expf(Ps[r][j] - mn);
                Ps[r][j] = p;
                lsum += p;
            }
            float a = __expf(mo - mn);
            rowa[r] = a;
            rowm[r] = mn;
            rowl[r] = rowl[r] * a + lsum;
        }
        __syncthreads();

        {   // ctx += P @ V  (each thread: row qr, 8 d-columns)
            const float aR = rowa[qr];
            #pragma unroll
            for (int j = 0; j < 8; j++) acc[j] *= aR;
            #pragma unroll 4
            for (int kc = 0; kc < 32; kc++) {
                const float p = Ps[qr][kc];
                float4 v0 = *(float4*)&Vs[kc][d8];
                float4 v1 = *(float4*)&Vs[kc][d8+4];
                acc[0] = fmaf(p, v0.x, acc[0]);
                acc[1] = fmaf(p, v0.y, acc[1]);
                acc[2] = fmaf(p, v0.z, acc[2]);
                acc[3] = fmaf(p, v0.w, acc[3]);
                acc[4] = fmaf(p, v1.x, acc[4]);
                acc[5] = fmaf(p, v1.y, acc[5]);
                acc[6] = fmaf(p, v1.z, acc[6]);
                acc[7] = fmaf(p, v1.w, acc[7]);
            }
        }
        __syncthreads();
    }

    // write ctx / l to [B, S, H] with heads merged
    const float invl = 1.0f / rowl[qr];
    const int s = qt*32 + qr;
    float* dst = CTX + ((size_t)(b*SEQ) + s) * HH + h*HDIM + d8;
    float4 o0, o1;
    o0.x = acc[0]*invl; o0.y = acc[1]*invl; o0.z = acc[2]*invl; o0.w = acc[3]*invl;
    o1.x = acc[4]*invl; o1.y = acc[5]*invl; o1.z = acc[6]*invl; o1.w = acc[7]*invl;
    *(float4*)(dst)     = o0;
    *(float4*)(dst + 4) = o1;
}

// ---------------------------------------------------------------------------
// In-place LayerNorm over rows of 768. One block per row.
// ---------------------------------------------------------------------------
__global__ __launch_bounds__(256)
void ln_kernel(float* __restrict__ y, const float* __restrict__ gamma,
               const float* __restrict__ beta)
{
    const int row = blockIdx.x;
    float* p = y + (size_t)row * HH;
    const int tid = threadIdx.x;

    float v[3];
    float s = 0.f, ss = 0.f;
    #pragma unroll
    for (int i = 0; i < 3; i++) {
        float x = p[tid + i*256];
        v[i] = x;
        s += x;
        ss += x * x;
    }
    #pragma unroll
    for (int off = 32; off > 0; off >>= 1) {
        s  += __shfl_down(s,  off);
        ss += __shfl_down(ss, off);
    }
    __shared__ float sbuf[4], ssbuf[4];
    __shared__ float mu_s, rstd_s;
    const int wave = tid >> 6;
    if ((tid & 63) == 0) { sbuf[wave] = s; ssbuf[wave] = ss; }
    __syncthreads();
    if (tid == 0) {
        float S  = sbuf[0] + sbuf[1] + sbuf[2] + sbuf[3];
        float SS = ssbuf[0] + ssbuf[1] + ssbuf[2] + ssbuf[3];
        float mu = S * (1.0f / HH);
        float var = SS * (1.0f / HH) - mu * mu;
        mu_s = mu;
        rstd_s = rsqrtf(var + 1e-5f);
    }
    __syncthreads();
    const float mu = mu_s, rstd = rstd_s;
    #pragma unroll
    for (int i = 0; i < 3; i++) {
        const int c = tid + i*256;
        p[c] = (v[i] - mu) * rstd * gamma[c] + beta[c];
    }
}

// ---------------------------------------------------------------------------
extern "C" void kernel_launch(void* const* d_in, const int* in_sizes, int n_in,
                              void* d_out, int out_size, void* d_ws, size_t ws_size,
                              hipStream_t stream)
{
    const float* x     = (const float*)d_in[0];
    const float* mask  = (const float*)d_in[1];
    const float* Wq    = (const float*)d_in[2];
    const float* bq    = (const float*)d_in[3];
    const float* Wk    = (const float*)d_in[4];
    const float* bk    = (const float*)d_in[5];
    const float* Wv    = (const float*)d_in[6];
    const float* bv    = (const float*)d_in[7];
    const float* Wo    = (const float*)d_in[8];
    const float* bo    = (const float*)d_in[9];
    const float* gamma = (const float*)d_in[10];
    const float* beta  = (const float*)d_in[11];

    float* ws = (float*)d_ws;
    const size_t per = (size_t)NB * NHEADS * SEQ * HDIM;  // 3,145,728 floats
    float* Qb  = ws;
    float* Kb  = ws + per;
    float* Vb  = ws + 2*per;
    float* CTX = ws + 3*per;
    float* out = (float*)d_out;

    dim3 gg(HH/64, (NB*SEQ)/64);   // (12, 64)
    gemm_qkv_kernel<<<gg, 256, 0, stream>>>(x, Wq, bq, Qb);
    gemm_qkv_kernel<<<gg, 256, 0, stream>>>(x, Wk, bk, Kb);
    gemm_qkv_kernel<<<gg, 256, 0, stream>>>(x, Wv, bv, Vb);

    attn_kernel<<<dim3(SEQ/32, NHEADS, NB), 256, 0, stream>>>(Qb, Kb, Vb, mask, CTX);

    gemm_proj_kernel<<<gg, 256, 0, stream>>>(CTX, Wo, bo, x, out);

    ln_kernel<<<NB*SEQ, 256, 0, stream>>>(out, gamma, beta);
}

// Round 2
// 930.161 us; speedup vs baseline: 1.9105x; 1.9105x over previous
//
#include <hip/hip_runtime.h>
#include <math.h>

#define HH 768
#define NHEADS 12
#define HDIM 64
#define SEQ 2048
#define NB 2

typedef __attribute__((ext_vector_type(8))) short s8v;
typedef __attribute__((ext_vector_type(4))) short s4v;
typedef __attribute__((ext_vector_type(4))) float f4v;

static __device__ inline short f2bf(float f) {
    union { float f; unsigned u; } v; v.f = f;
    unsigned r = v.u + 0x7fff + ((v.u >> 16) & 1);   // RNE
    return (short)(r >> 16);
}

// ---------------------------------------------------------------------------
// fp32 GEMM (BT form), bf16 output. MODE 0: [B,NH,S,HD] (*scale). MODE 1: V^T [B,NH,HD,S].
// ---------------------------------------------------------------------------
template<int MODE>
__global__ __launch_bounds__(256)
void gemm_qkv_bf16(const float* __restrict__ X, const float* __restrict__ W,
                   const float* __restrict__ bias, short* __restrict__ out, float scale)
{
    __shared__ float As[64][20];
    __shared__ float Ws[64][20];
    const int tid = threadIdx.x;
    const int n0 = blockIdx.x * 64;
    const int m0 = blockIdx.y * 64;
    const int ty = tid >> 4;
    const int tx = tid & 15;
    const int lr = tid >> 2;
    const int lc = (tid & 3) << 2;
    float acc[4][4] = {};

    for (int k0 = 0; k0 < HH; k0 += 16) {
        float4 av = *(const float4*)(X + (size_t)(m0 + lr) * HH + k0 + lc);
        float4 wv = *(const float4*)(W + (size_t)(n0 + lr) * HH + k0 + lc);
        *(float4*)&As[lr][lc] = av;
        *(float4*)&Ws[lr][lc] = wv;
        __syncthreads();
        #pragma unroll
        for (int kk = 0; kk < 16; kk++) {
            float a[4], bv[4];
            #pragma unroll
            for (int i = 0; i < 4; i++) a[i] = As[ty*4+i][kk];
            #pragma unroll
            for (int j = 0; j < 4; j++) bv[j] = Ws[tx*4+j][kk];
            #pragma unroll
            for (int i = 0; i < 4; i++)
                #pragma unroll
                for (int j = 0; j < 4; j++)
                    acc[i][j] = fmaf(a[i], bv[j], acc[i][j]);
        }
        __syncthreads();
    }

    const int hh = n0 >> 6;            // one head per 64-col block
    #pragma unroll
    for (int i = 0; i < 4; i++) {
        const int gm = m0 + ty*4 + i;
        const int bb = gm >> 11;
        const int s  = gm & 2047;
        if (MODE == 0) {
            s4v pk;
            #pragma unroll
            for (int j = 0; j < 4; j++) {
                const int n = n0 + tx*4 + j;
                pk[j] = f2bf((acc[i][j] + bias[n]) * scale);
            }
            *(s4v*)(out + ((size_t)((bb*NHEADS + hh)*SEQ) + s)*HDIM + tx*4) = pk;
        } else {
            #pragma unroll
            for (int j = 0; j < 4; j++) {
                const int n = n0 + tx*4 + j;
                const int d = tx*4 + j;
                out[((size_t)((bb*NHEADS + hh)*HDIM) + d)*SEQ + s] = f2bf(acc[i][j] + bias[n]);
            }
        }
    }
}

// ---------------------------------------------------------------------------
// Out-projection (fp32) + residual.
// ---------------------------------------------------------------------------
__global__ __launch_bounds__(256)
void gemm_proj_kernel(const float* __restrict__ CTX, const float* __restrict__ W,
                      const float* __restrict__ bias, const float* __restrict__ X,
                      float* __restrict__ out)
{
    __shared__ float As[64][20];
    __shared__ float Ws[64][20];
    const int tid = threadIdx.x;
    const int n0 = blockIdx.x * 64;
    const int m0 = blockIdx.y * 64;
    const int ty = tid >> 4;
    const int tx = tid & 15;
    const int lr = tid >> 2;
    const int lc = (tid & 3) << 2;
    float acc[4][4] = {};

    for (int k0 = 0; k0 < HH; k0 += 16) {
        float4 av = *(const float4*)(CTX + (size_t)(m0 + lr) * HH + k0 + lc);
        float4 wv = *(const float4*)(W   + (size_t)(n0 + lr) * HH + k0 + lc);
        *(float4*)&As[lr][lc] = av;
        *(float4*)&Ws[lr][lc] = wv;
        __syncthreads();
        #pragma unroll
        for (int kk = 0; kk < 16; kk++) {
            float a[4], bv[4];
            #pragma unroll
            for (int i = 0; i < 4; i++) a[i] = As[ty*4+i][kk];
            #pragma unroll
            for (int j = 0; j < 4; j++) bv[j] = Ws[tx*4+j][kk];
            #pragma unroll
            for (int i = 0; i < 4; i++)
                #pragma unroll
                for (int j = 0; j < 4; j++)
                    acc[i][j] = fmaf(a[i], bv[j], acc[i][j]);
        }
        __syncthreads();
    }

    #pragma unroll
    for (int i = 0; i < 4; i++) {
        const int gm = m0 + ty*4 + i;
        #pragma unroll
        for (int j = 0; j < 4; j++) {
            const int n = n0 + tx*4 + j;
            out[(size_t)gm * HH + n] = acc[i][j] + bias[n] + X[(size_t)gm * HH + n];
        }
    }
}

// ---------------------------------------------------------------------------
// Flash attention, bf16 MFMA. Block = (b, h, 64 q-rows); 4 waves (16 q each).
// Q/K: [B,NH,S,HD] bf16 (Q pre-scaled by 1/8). VT: [B,NH,HD,S] bf16.
// CTX out: [B,S,H] fp32.
// ---------------------------------------------------------------------------
__global__ __launch_bounds__(256)
void attn_mfma(const short* __restrict__ Q, const short* __restrict__ K,
               const short* __restrict__ VT, const float* __restrict__ mask,
               float* __restrict__ CTX)
{
    const int qt = blockIdx.x;
    const int h  = blockIdx.y;
    const int b  = blockIdx.z;
    const size_t hb = (size_t)(b * NHEADS + h);
    const short* Qg  = Q  + hb * SEQ * HDIM;
    const short* Kg  = K  + hb * SEQ * HDIM;
    const short* VTg = VT + hb * HDIM * SEQ;

    __shared__ __align__(16) char KsB[8192];    // 64 rows x 128B, XOR-swizzled
    __shared__ __align__(16) char VTsB[8192];   // 64 rows x 128B, XOR-swizzled
    __shared__ __align__(16) char PlsB[4][2048];// per-wave P: 16 rows x 128B, swizzled

    const int tid  = threadIdx.x;
    const int w    = tid >> 6;
    const int lane = tid & 63;
    const int g    = lane >> 4;
    const int r    = lane & 15;
    const int q0   = qt * 64;

    // Q fragments in registers (A-frag: lane -> Q[row=r][8g+i(+32h)])
    const short* qrow = Qg + (size_t)(q0 + w*16 + r) * HDIM;
    const s8v qf0 = *(const s8v*)(qrow + 8*g);
    const s8v qf1 = *(const s8v*)(qrow + 8*g + 32);

    f4v acc[4];
    #pragma unroll
    for (int t = 0; t < 4; t++) acc[t] = (f4v){0.f, 0.f, 0.f, 0.f};
    float mrow[4] = {-1e30f, -1e30f, -1e30f, -1e30f};
    float lrow[4] = {0.f, 0.f, 0.f, 0.f};

    s8v kr0, kr1, vr0, vr1;
    const int sr0 = tid >> 3;          // staging row 0..31
    const int sce = (tid & 7) * 8;     // staging col (elements)
    const int scb = (tid & 7) * 16;    // staging col (bytes)

    #define LOADT(K0) do {                                                   \
        kr0 = *(const s8v*)(Kg  + (size_t)((K0) + sr0)      * HDIM + sce);   \
        kr1 = *(const s8v*)(Kg  + (size_t)((K0) + sr0 + 32) * HDIM + sce);   \
        vr0 = *(const s8v*)(VTg + (size_t)(sr0)      * SEQ + (K0) + sce);    \
        vr1 = *(const s8v*)(VTg + (size_t)(sr0 + 32) * SEQ + (K0) + sce);    \
    } while (0)

    #define STORET() do {                                                    \
        *(s8v*)(KsB  + sr0*128        + (scb ^ ((sr0 & 7) << 4)))        = kr0; \
        *(s8v*)(VTsB + sr0*128        + (scb ^ ((sr0 & 7) << 4)))        = vr0; \
        *(s8v*)(KsB  + (sr0+32)*128   + (scb ^ (((sr0+32) & 7) << 4)))   = kr1; \
        *(s8v*)(VTsB + (sr0+32)*128   + (scb ^ (((sr0+32) & 7) << 4)))   = vr1; \
    } while (0)

    LOADT(0);
    for (int kt = 0; kt < SEQ/64; ++kt) {
        __syncthreads();               // LDS free (prev tile consumed)
        STORET();
        if (kt + 1 < SEQ/64) LOADT((kt + 1) * 64);
        __syncthreads();               // LDS ready

        const int k0 = kt * 64;
        float madd[4];
        #pragma unroll
        for (int j = 0; j < 4; j++)
            madd[j] = (1.0f - mask[b*SEQ + k0 + 16*j + r]) * -10000.0f;

        // ---- QK^T: S[q=4g+i][k=16j+r] ----
        f4v sj[4];
        #pragma unroll
        for (int j = 0; j < 4; j++) {
            const int krow = 16*j + r;
            const char* kb = KsB + krow * 128;
            const int sw = (krow & 7) << 4;
            s8v kf0 = *(const s8v*)(kb + ((16*g)      ^ sw));
            s8v kf1 = *(const s8v*)(kb + ((16*g + 64) ^ sw));
            f4v z = (f4v){0.f, 0.f, 0.f, 0.f};
            z = __builtin_amdgcn_mfma_f32_16x16x32_bf16(qf0, kf0, z, 0, 0, 0);
            z = __builtin_amdgcn_mfma_f32_16x16x32_bf16(qf1, kf1, z, 0, 0, 0);
            #pragma unroll
            for (int i = 0; i < 4; i++) z[i] += madd[j];
            sj[j] = z;
        }

        // ---- online softmax (rows lane-local: 4g+i; reduce over 16-lane group) ----
        float alpha[4];
        #pragma unroll
        for (int i = 0; i < 4; i++) {
            float rm = fmaxf(fmaxf(sj[0][i], sj[1][i]), fmaxf(sj[2][i], sj[3][i]));
            rm = fmaxf(rm, __shfl_xor(rm, 1));
            rm = fmaxf(rm, __shfl_xor(rm, 2));
            rm = fmaxf(rm, __shfl_xor(rm, 4));
            rm = fmaxf(rm, __shfl_xor(rm, 8));
            const float mn = fmaxf(mrow[i], rm);
            alpha[i] = __expf(mrow[i] - mn);
            mrow[i] = mn;
        }
        #pragma unroll
        for (int j = 0; j < 4; j++)
            #pragma unroll
            for (int i = 0; i < 4; i++)
                sj[j][i] = __expf(sj[j][i] - mrow[i]);
        #pragma unroll
        for (int i = 0; i < 4; i++) {
            float rs = (sj[0][i] + sj[1][i]) + (sj[2][i] + sj[3][i]);
            rs += __shfl_xor(rs, 1);
            rs += __shfl_xor(rs, 2);
            rs += __shfl_xor(rs, 4);
            rs += __shfl_xor(rs, 8);
            lrow[i] = lrow[i] * alpha[i] + rs;
        }

        // ---- P -> bf16 -> per-wave LDS (swizzled) ----
        char* pb = PlsB[w];
        #pragma unroll
        for (int i = 0; i < 4; i++) {
            const int prow = 4*g + i;
            char* base = pb + prow * 128;
            const int sw = (prow & 7) << 4;
            #pragma unroll
            for (int j = 0; j < 4; j++)
                *(short*)(base + (((16*j + r) * 2) ^ sw)) = f2bf(sj[j][i]);
        }

        // ---- rescale ctx, then ctx += P @ V ----
        #pragma unroll
        for (int t = 0; t < 4; t++)
            #pragma unroll
            for (int i = 0; i < 4; i++)
                acc[t][i] *= alpha[i];

        #pragma unroll
        for (int c = 0; c < 2; c++) {
            s8v pf = *(const s8v*)(pb + r*128 + ((16*g + 64*c) ^ ((r & 7) << 4)));
            #pragma unroll
            for (int t = 0; t < 4; t++) {
                const int vrow = 16*t + r;
                s8v vf = *(const s8v*)(VTsB + vrow*128 + ((16*g + 64*c) ^ ((vrow & 7) << 4)));
                acc[t] = __builtin_amdgcn_mfma_f32_16x16x32_bf16(pf, vf, acc[t], 0, 0, 0);
            }
        }
    }

    // ---- epilogue: /l, write ctx[q][d] (q = q0+w*16+4g+i, d = 16t+r) ----
    #pragma unroll
    for (int i = 0; i < 4; i++) {
        const float invl = 1.0f / lrow[i];
        const size_t rowbase = ((size_t)(b*SEQ) + q0 + w*16 + 4*g + i) * HH + h*HDIM;
        #pragma unroll
        for (int t = 0; t < 4; t++)
            CTX[rowbase + 16*t + r] = acc[t][i] * invl;
    }
    #undef LOADT
    #undef STORET
}

// ---------------------------------------------------------------------------
// In-place LayerNorm over rows of 768.
// ---------------------------------------------------------------------------
__global__ __launch_bounds__(256)
void ln_kernel(float* __restrict__ y, const float* __restrict__ gamma,
               const float* __restrict__ beta)
{
    const int row = blockIdx.x;
    float* p = y + (size_t)row * HH;
    const int tid = threadIdx.x;

    float v[3];
    float s = 0.f, ss = 0.f;
    #pragma unroll
    for (int i = 0; i < 3; i++) {
        float x = p[tid + i*256];
        v[i] = x;
        s += x;
        ss += x * x;
    }
    #pragma unroll
    for (int off = 32; off > 0; off >>= 1) {
        s  += __shfl_down(s,  off);
        ss += __shfl_down(ss, off);
    }
    __shared__ float sbuf[4], ssbuf[4];
    __shared__ float mu_s, rstd_s;
    const int wave = tid >> 6;
    if ((tid & 63) == 0) { sbuf[wave] = s; ssbuf[wave] = ss; }
    __syncthreads();
    if (tid == 0) {
        float S  = sbuf[0] + sbuf[1] + sbuf[2] + sbuf[3];
        float SS = ssbuf[0] + ssbuf[1] + ssbuf[2] + ssbuf[3];
        float mu = S * (1.0f / HH);
        float var = SS * (1.0f / HH) - mu * mu;
        mu_s = mu;
        rstd_s = rsqrtf(var + 1e-5f);
    }
    __syncthreads();
    const float mu = mu_s, rstd = rstd_s;
    #pragma unroll
    for (int i = 0; i < 3; i++) {
        const int c = tid + i*256;
        p[c] = (v[i] - mu) * rstd * gamma[c] + beta[c];
    }
}

// ---------------------------------------------------------------------------
extern "C" void kernel_launch(void* const* d_in, const int* in_sizes, int n_in,
                              void* d_out, int out_size, void* d_ws, size_t ws_size,
                              hipStream_t stream)
{
    const float* x     = (const float*)d_in[0];
    const float* mask  = (const float*)d_in[1];
    const float* Wq    = (const float*)d_in[2];
    const float* bq    = (const float*)d_in[3];
    const float* Wk    = (const float*)d_in[4];
    const float* bk    = (const float*)d_in[5];
    const float* Wv    = (const float*)d_in[6];
    const float* bv    = (const float*)d_in[7];
    const float* Wo    = (const float*)d_in[8];
    const float* bo    = (const float*)d_in[9];
    const float* gamma = (const float*)d_in[10];
    const float* beta  = (const float*)d_in[11];

    const size_t per = (size_t)NB * NHEADS * SEQ * HDIM;   // 3,145,728 elems
    short* Qb  = (short*)d_ws;
    short* Kb  = Qb + per;
    short* Vb  = Kb + per;
    float* CTX = (float*)((char*)d_ws + 3 * per * sizeof(short));
    float* out = (float*)d_out;

    dim3 gg(HH/64, (NB*SEQ)/64);
    gemm_qkv_bf16<0><<<gg, 256, 0, stream>>>(x, Wq, bq, Qb, 0.125f);
    gemm_qkv_bf16<0><<<gg, 256, 0, stream>>>(x, Wk, bk, Kb, 1.0f);
    gemm_qkv_bf16<1><<<gg, 256, 0, stream>>>(x, Wv, bv, Vb, 1.0f);

    attn_mfma<<<dim3(SEQ/64, NHEADS, NB), 256, 0, stream>>>(Qb, Kb, Vb, mask, CTX);

    gemm_proj_kernel<<<gg, 256, 0, stream>>>(CTX, Wo, bo, x, out);

    ln_kernel<<<NB*SEQ, 256, 0, stream>>>(out, gamma, beta);
}

// Round 3
// 180.883 us; speedup vs baseline: 9.8243x; 5.1424x over previous
//
#include <hip/hip_runtime.h>
#include <math.h>

#define HH 768
#define NHEADS 12
#define HDIM 64
#define SEQ 2048
#define NB 2

typedef __attribute__((ext_vector_type(8))) short s8v;
typedef __attribute__((ext_vector_type(4))) short s4v;
typedef __attribute__((ext_vector_type(4))) float f4v;

static __device__ inline short f2bf(float f) {
    union { float f; unsigned u; } v; v.f = f;
    unsigned r = v.u + 0x7fff + ((v.u >> 16) & 1);   // RNE
    return (short)(r >> 16);
}

// async global->LDS, 16B per lane. LDS base must be wave-uniform.
__device__ __forceinline__ void gld16(const void* g, void* l) {
    __builtin_amdgcn_global_load_lds(
        (const __attribute__((address_space(1))) void*)g,
        (__attribute__((address_space(3))) void*)l, 16, 0, 0);
}

// ---------------------------------------------------------------------------
// fp32 -> bf16 conversion: X (4096x768) and the 4 weight matrices (768x768).
// ---------------------------------------------------------------------------
#define XV8   393216   // X elems/8
#define WV8   73728    // W elems/8
__global__ __launch_bounds__(256)
void cvt_kernel(const float* __restrict__ X, short* __restrict__ Xb,
                const float* __restrict__ W0, short* __restrict__ W0b,
                const float* __restrict__ W1, short* __restrict__ W1b,
                const float* __restrict__ W2, short* __restrict__ W2b,
                const float* __restrict__ W3, short* __restrict__ W3b)
{
    int gid = blockIdx.x * 256 + threadIdx.x;
    const float* src; short* dst; size_t off;
    if      (gid < XV8)            { src = X;  dst = Xb;  off = gid; }
    else if (gid < XV8 + WV8)      { src = W0; dst = W0b; off = gid - XV8; }
    else if (gid < XV8 + 2*WV8)    { src = W1; dst = W1b; off = gid - XV8 - WV8; }
    else if (gid < XV8 + 3*WV8)    { src = W2; dst = W2b; off = gid - XV8 - 2*WV8; }
    else if (gid < XV8 + 4*WV8)    { src = W3; dst = W3b; off = gid - XV8 - 3*WV8; }
    else return;
    off *= 8;
    float4 a = *(const float4*)(src + off);
    float4 b = *(const float4*)(src + off + 4);
    s8v o;
    o[0] = f2bf(a.x); o[1] = f2bf(a.y); o[2] = f2bf(a.z); o[3] = f2bf(a.w);
    o[4] = f2bf(b.x); o[5] = f2bf(b.y); o[6] = f2bf(b.z); o[7] = f2bf(b.w);
    *(s8v*)(dst + off) = o;
}

// ---------------------------------------------------------------------------
// MFMA GEMM, 128x128 tile, BK=32, 4 waves (2x2, 64x64 each), m97 structure.
// C[m,n] = sum_k A[m,k] * W[n,k]   (A: [M,768] bf16, W: [768,768] bf16)
// EPI 0: fused QKV -> bf16 [B,NH,S,HD], Q scaled by 0.125.
// EPI 1: out-proj -> fp32 [4096,768] + bias + residual.
// ---------------------------------------------------------------------------
template<int EPI>
__global__ __launch_bounds__(256)
void gemm_mfma(const short* __restrict__ A,
               const short* __restrict__ Wq, const short* __restrict__ Wk,
               const short* __restrict__ Wv,
               const float* __restrict__ bq, const float* __restrict__ bk,
               const float* __restrict__ bv,
               short* __restrict__ Qo, short* __restrict__ Ko, short* __restrict__ Vo,
               const float* __restrict__ Xres, float* __restrict__ Fo)
{
    __shared__ __align__(16) short As[128*32];
    __shared__ __align__(16) short Bs[128*32];

    const int tid  = threadIdx.x;
    const int w    = tid >> 6;
    const int lane = tid & 63;
    const int g    = lane >> 4;
    const int r    = lane & 15;
    const int wr   = w >> 1;
    const int wc   = w & 1;
    const int m0   = blockIdx.y * 128;

    int n0;
    const short* Wb; const float* bias; short* outp; float scale;
    if (EPI == 0) {
        const int seg = blockIdx.x / 6;
        n0 = (blockIdx.x % 6) * 128;
        Wb   = seg == 0 ? Wq : seg == 1 ? Wk : Wv;
        bias = seg == 0 ? bq : seg == 1 ? bk : bv;
        outp = seg == 0 ? Qo : seg == 1 ? Ko : Vo;
        scale = seg == 0 ? 0.125f : 1.0f;
    } else {
        n0 = blockIdx.x * 128;
        Wb = Wq; bias = bq; outp = nullptr; scale = 1.0f;
    }

    // staging addresses: wave w stages rows [w*32, w*32+32) of each tile
    const int lrow = lane >> 2;          // 0..15
    const int lcol = (lane & 3) * 8;     // elem offset in K
    const short* Ag0 = A  + (size_t)(m0 + w*32 + lrow) * HH + lcol;
    const short* Bg0 = Wb + (size_t)(n0 + w*32 + lrow) * HH + lcol;
    short* Al0 = As + (w*32)      * 32;
    short* Al1 = As + (w*32 + 16) * 32;
    short* Bl0 = Bs + (w*32)      * 32;
    short* Bl1 = Bs + (w*32 + 16) * 32;

    f4v acc[4][4];
    #pragma unroll
    for (int i = 0; i < 4; i++)
        #pragma unroll
        for (int j = 0; j < 4; j++) acc[i][j] = (f4v){0.f,0.f,0.f,0.f};

    for (int kt = 0; kt < HH/32; ++kt) {
        const int k0 = kt * 32;
        gld16(Ag0 + k0,           Al0);
        gld16(Ag0 + k0 + 16*HH,   Al1);
        gld16(Bg0 + k0,           Bl0);
        gld16(Bg0 + k0 + 16*HH,   Bl1);
        __syncthreads();     // drains vmcnt before barrier (compiler-inserted)

        s8v af[4], bf[4];
        #pragma unroll
        for (int mi = 0; mi < 4; mi++)
            af[mi] = *(const s8v*)(As + (wr*64 + mi*16 + r)*32 + g*8);
        #pragma unroll
        for (int ni = 0; ni < 4; ni++)
            bf[ni] = *(const s8v*)(Bs + (wc*64 + ni*16 + r)*32 + g*8);
        #pragma unroll
        for (int mi = 0; mi < 4; mi++)
            #pragma unroll
            for (int ni = 0; ni < 4; ni++)
                acc[mi][ni] = __builtin_amdgcn_mfma_f32_16x16x32_bf16(af[mi], bf[ni], acc[mi][ni], 0, 0, 0);
        __syncthreads();
    }

    if (EPI == 0) {
        #pragma unroll
        for (int mi = 0; mi < 4; mi++) {
            #pragma unroll
            for (int j = 0; j < 4; j++) {
                const int m = m0 + wr*64 + mi*16 + 4*g + j;
                const int bb = m >> 11;
                const int s  = m & 2047;
                #pragma unroll
                for (int ni = 0; ni < 4; ni++) {
                    const int n = n0 + wc*64 + ni*16 + r;
                    const int h = n >> 6;
                    const int d = n & 63;
                    outp[((size_t)((bb*NHEADS + h)*SEQ) + s)*HDIM + d] =
                        f2bf((acc[mi][ni][j] + bias[n]) * scale);
                }
            }
        }
    } else {
        #pragma unroll
        for (int mi = 0; mi < 4; mi++) {
            #pragma unroll
            for (int j = 0; j < 4; j++) {
                const int m = m0 + wr*64 + mi*16 + 4*g + j;
                #pragma unroll
                for (int ni = 0; ni < 4; ni++) {
                    const int n = n0 + wc*64 + ni*16 + r;
                    Fo[(size_t)m*HH + n] = acc[mi][ni][j] + bias[n] + Xres[(size_t)m*HH + n];
                }
            }
        }
    }
}

// ---------------------------------------------------------------------------
// V [B,NH,S,HD] -> VT [B,NH,HD,S], 64x64 LDS tiles.
// ---------------------------------------------------------------------------
__global__ __launch_bounds__(256)
void vtrans_kernel(const short* __restrict__ V, short* __restrict__ VT)
{
    const int st = blockIdx.x;   // 0..31
    const int h  = blockIdx.y;
    const int b  = blockIdx.z;
    __shared__ short T[64][72];
    const int t = threadIdx.x;
    const short* src = V + ((size_t)(b*NHEADS + h)*SEQ + st*64) * HDIM;

    {
        const int sl = t >> 2;            // 0..63
        const int dq = (t & 3) * 16;      // 0,16,32,48
        s8v a = *(const s8v*)(src + sl*HDIM + dq);
        s8v c = *(const s8v*)(src + sl*HDIM + dq + 8);
        #pragma unroll
        for (int i = 0; i < 8; i++) { T[dq+i][sl] = a[i]; T[dq+8+i][sl] = c[i]; }
    }
    __syncthreads();
    {
        const int d  = t >> 2;            // 0..63
        const int sq = (t & 3) * 16;
        s8v o0 = *(const s8v*)&T[d][sq];
        s8v o1 = *(const s8v*)&T[d][sq+8];
        short* dst = VT + ((size_t)(b*NHEADS + h)*HDIM + d)*SEQ + st*64 + sq;
        *(s8v*)(dst)     = o0;
        *(s8v*)(dst + 8) = o1;
    }
}

// ---------------------------------------------------------------------------
// Flash attention, bf16 MFMA. Block = (b, h, 64 q-rows); 4 waves (16 q each).
// Q/K: [B,NH,S,HD] bf16 (Q pre-scaled by 1/8). VT: [B,NH,HD,S] bf16.
// CTX out: [B,S,H] bf16.
// ---------------------------------------------------------------------------
__global__ __launch_bounds__(256)
void attn_mfma(const short* __restrict__ Q, const short* __restrict__ K,
               const short* __restrict__ VT, const float* __restrict__ mask,
               short* __restrict__ CTX)
{
    const int qt = blockIdx.x;
    const int h  = blockIdx.y;
    const int b  = blockIdx.z;
    const size_t hb = (size_t)(b * NHEADS + h);
    const short* Qg  = Q  + hb * SEQ * HDIM;
    const short* Kg  = K  + hb * SEQ * HDIM;
    const short* VTg = VT + hb * HDIM * SEQ;

    __shared__ __align__(16) char KsB[8192];
    __shared__ __align__(16) char VTsB[8192];
    __shared__ __align__(16) char PlsB[4][2048];

    const int tid  = threadIdx.x;
    const int w    = tid >> 6;
    const int lane = tid & 63;
    const int g    = lane >> 4;
    const int r    = lane & 15;
    const int q0   = qt * 64;

    const short* qrow = Qg + (size_t)(q0 + w*16 + r) * HDIM;
    const s8v qf0 = *(const s8v*)(qrow + 8*g);
    const s8v qf1 = *(const s8v*)(qrow + 8*g + 32);

    f4v acc[4];
    #pragma unroll
    for (int t = 0; t < 4; t++) acc[t] = (f4v){0.f, 0.f, 0.f, 0.f};
    float mrow[4] = {-1e30f, -1e30f, -1e30f, -1e30f};
    float lrow[4] = {0.f, 0.f, 0.f, 0.f};

    s8v kr0, kr1, vr0, vr1;
    const int sr0 = tid >> 3;
    const int sce = (tid & 7) * 8;
    const int scb = (tid & 7) * 16;

    #define LOADT(K0) do {                                                   \
        kr0 = *(const s8v*)(Kg  + (size_t)((K0) + sr0)      * HDIM + sce);   \
        kr1 = *(const s8v*)(Kg  + (size_t)((K0) + sr0 + 32) * HDIM + sce);   \
        vr0 = *(const s8v*)(VTg + (size_t)(sr0)      * SEQ + (K0) + sce);    \
        vr1 = *(const s8v*)(VTg + (size_t)(sr0 + 32) * SEQ + (K0) + sce);    \
    } while (0)

    #define STORET() do {                                                    \
        *(s8v*)(KsB  + sr0*128        + (scb ^ ((sr0 & 7) << 4)))        = kr0; \
        *(s8v*)(VTsB + sr0*128        + (scb ^ ((sr0 & 7) << 4)))        = vr0; \
        *(s8v*)(KsB  + (sr0+32)*128   + (scb ^ (((sr0+32) & 7) << 4)))   = kr1; \
        *(s8v*)(VTsB + (sr0+32)*128   + (scb ^ (((sr0+32) & 7) << 4)))   = vr1; \
    } while (0)

    LOADT(0);
    for (int kt = 0; kt < SEQ/64; ++kt) {
        __syncthreads();
        STORET();
        if (kt + 1 < SEQ/64) LOADT((kt + 1) * 64);
        __syncthreads();

        const int k0 = kt * 64;
        float madd[4];
        #pragma unroll
        for (int j = 0; j < 4; j++)
            madd[j] = (1.0f - mask[b*SEQ + k0 + 16*j + r]) * -10000.0f;

        f4v sj[4];
        #pragma unroll
        for (int j = 0; j < 4; j++) {
            const int krow = 16*j + r;
            const char* kb = KsB + krow * 128;
            const int sw = (krow & 7) << 4;
            s8v kf0 = *(const s8v*)(kb + ((16*g)      ^ sw));
            s8v kf1 = *(const s8v*)(kb + ((16*g + 64) ^ sw));
            f4v z = (f4v){0.f, 0.f, 0.f, 0.f};
            z = __builtin_amdgcn_mfma_f32_16x16x32_bf16(qf0, kf0, z, 0, 0, 0);
            z = __builtin_amdgcn_mfma_f32_16x16x32_bf16(qf1, kf1, z, 0, 0, 0);
            #pragma unroll
            for (int i = 0; i < 4; i++) z[i] += madd[j];
            sj[j] = z;
        }

        float alpha[4];
        #pragma unroll
        for (int i = 0; i < 4; i++) {
            float rm = fmaxf(fmaxf(sj[0][i], sj[1][i]), fmaxf(sj[2][i], sj[3][i]));
            rm = fmaxf(rm, __shfl_xor(rm, 1));
            rm = fmaxf(rm, __shfl_xor(rm, 2));
            rm = fmaxf(rm, __shfl_xor(rm, 4));
            rm = fmaxf(rm, __shfl_xor(rm, 8));
            const float mn = fmaxf(mrow[i], rm);
            alpha[i] = __expf(mrow[i] - mn);
            mrow[i] = mn;
        }
        #pragma unroll
        for (int j = 0; j < 4; j++)
            #pragma unroll
            for (int i = 0; i < 4; i++)
                sj[j][i] = __expf(sj[j][i] - mrow[i]);
        #pragma unroll
        for (int i = 0; i < 4; i++) {
            float rs = (sj[0][i] + sj[1][i]) + (sj[2][i] + sj[3][i]);
            rs += __shfl_xor(rs, 1);
            rs += __shfl_xor(rs, 2);
            rs += __shfl_xor(rs, 4);
            rs += __shfl_xor(rs, 8);
            lrow[i] = lrow[i] * alpha[i] + rs;
        }

        char* pb = PlsB[w];
        #pragma unroll
        for (int i = 0; i < 4; i++) {
            const int prow = 4*g + i;
            char* base = pb + prow * 128;
            const int sw = (prow & 7) << 4;
            #pragma unroll
            for (int j = 0; j < 4; j++)
                *(short*)(base + (((16*j + r) * 2) ^ sw)) = f2bf(sj[j][i]);
        }

        #pragma unroll
        for (int t = 0; t < 4; t++)
            #pragma unroll
            for (int i = 0; i < 4; i++)
                acc[t][i] *= alpha[i];

        #pragma unroll
        for (int c = 0; c < 2; c++) {
            s8v pf = *(const s8v*)(pb + r*128 + ((16*g + 64*c) ^ ((r & 7) << 4)));
            #pragma unroll
            for (int t = 0; t < 4; t++) {
                const int vrow = 16*t + r;
                s8v vf = *(const s8v*)(VTsB + vrow*128 + ((16*g + 64*c) ^ ((vrow & 7) << 4)));
                acc[t] = __builtin_amdgcn_mfma_f32_16x16x32_bf16(pf, vf, acc[t], 0, 0, 0);
            }
        }
    }

    #pragma unroll
    for (int i = 0; i < 4; i++) {
        const float invl = 1.0f / lrow[i];
        const size_t rowbase = ((size_t)(b*SEQ) + q0 + w*16 + 4*g + i) * HH + h*HDIM;
        #pragma unroll
        for (int t = 0; t < 4; t++)
            CTX[rowbase + 16*t + r] = f2bf(acc[t][i] * invl);
    }
    #undef LOADT
    #undef STORET
}

// ---------------------------------------------------------------------------
// In-place LayerNorm over rows of 768.
// ---------------------------------------------------------------------------
__global__ __launch_bounds__(256)
void ln_kernel(float* __restrict__ y, const float* __restrict__ gamma,
               const float* __restrict__ beta)
{
    const int row = blockIdx.x;
    float* p = y + (size_t)row * HH;
    const int tid = threadIdx.x;

    float v[3];
    float s = 0.f, ss = 0.f;
    #pragma unroll
    for (int i = 0; i < 3; i++) {
        float x = p[tid + i*256];
        v[i] = x;
        s += x;
        ss += x * x;
    }
    #pragma unroll
    for (int off = 32; off > 0; off >>= 1) {
        s  += __shfl_down(s,  off);
        ss += __shfl_down(ss, off);
    }
    __shared__ float sbuf[4], ssbuf[4];
    __shared__ float mu_s, rstd_s;
    const int wave = tid >> 6;
    if ((tid & 63) == 0) { sbuf[wave] = s; ssbuf[wave] = ss; }
    __syncthreads();
    if (tid == 0) {
        float S  = sbuf[0] + sbuf[1] + sbuf[2] + sbuf[3];
        float SS = ssbuf[0] + ssbuf[1] + ssbuf[2] + ssbuf[3];
        float mu = S * (1.0f / HH);
        float var = SS * (1.0f / HH) - mu * mu;
        mu_s = mu;
        rstd_s = rsqrtf(var + 1e-5f);
    }
    __syncthreads();
    const float mu = mu_s, rstd = rstd_s;
    #pragma unroll
    for (int i = 0; i < 3; i++) {
        const int c = tid + i*256;
        p[c] = (v[i] - mu) * rstd * gamma[c] + beta[c];
    }
}

// ---------------------------------------------------------------------------
extern "C" void kernel_launch(void* const* d_in, const int* in_sizes, int n_in,
                              void* d_out, int out_size, void* d_ws, size_t ws_size,
                              hipStream_t stream)
{
    const float* x     = (const float*)d_in[0];
    const float* mask  = (const float*)d_in[1];
    const float* Wq    = (const float*)d_in[2];
    const float* bq    = (const float*)d_in[3];
    const float* Wk    = (const float*)d_in[4];
    const float* bk    = (const float*)d_in[5];
    const float* Wv    = (const float*)d_in[6];
    const float* bv    = (const float*)d_in[7];
    const float* Wo    = (const float*)d_in[8];
    const float* bo    = (const float*)d_in[9];
    const float* gamma = (const float*)d_in[10];
    const float* beta  = (const float*)d_in[11];

    const size_t PER = (size_t)NB * NHEADS * SEQ * HDIM;  // 3,145,728
    const size_t WSZ = (size_t)HH * HH;                   // 589,824
    short* wsS  = (short*)d_ws;
    short* Xb   = wsS;          // region 0: Xb, later reused as VTb
    short* VTb  = wsS;
    short* Wqb  = wsS + PER;
    short* Wkb  = Wqb + WSZ;
    short* Wvb  = Wkb + WSZ;
    short* Wob  = Wvb + WSZ;
    short* Qb   = Wob + WSZ;
    short* Kb   = Qb + PER;
    short* Vb   = Kb + PER;     // region reused as CTXb after vtrans+attn
    short* CTXb = Vb;
    float* out  = (float*)d_out;

    cvt_kernel<<<2688, 256, 0, stream>>>(x, Xb, Wq, Wqb, Wk, Wkb, Wv, Wvb, Wo, Wob);

    gemm_mfma<0><<<dim3(18, 32), 256, 0, stream>>>(
        Xb, Wqb, Wkb, Wvb, bq, bk, bv, Qb, Kb, Vb, nullptr, nullptr);

    vtrans_kernel<<<dim3(SEQ/64, NHEADS, NB), 256, 0, stream>>>(Vb, VTb);

    attn_mfma<<<dim3(SEQ/64, NHEADS, NB), 256, 0, stream>>>(Qb, Kb, VTb, mask, CTXb);

    gemm_mfma<1><<<dim3(6, 32), 256, 0, stream>>>(
        CTXb, Wob, nullptr, nullptr, bo, nullptr, nullptr,
        nullptr, nullptr, nullptr, x, out);

    ln_kernel<<<NB*SEQ, 256, 0, stream>>>(out, gamma, beta);
}

// Round 4
// 166.394 us; speedup vs baseline: 10.6797x; 1.0871x over previous
//
#include <hip/hip_runtime.h>
#include <math.h>

#define HH 768
#define NHEADS 12
#define HDIM 64
#define SEQ 2048
#define NB 2
#define L2E 1.44269504088896f

typedef __attribute__((ext_vector_type(8))) short s8v;
typedef __attribute__((ext_vector_type(4))) short s4v;
typedef __attribute__((ext_vector_type(4))) float f4v;

static __device__ inline short f2bf(float f) {
    union { float f; unsigned u; } v; v.f = f;
    unsigned r = v.u + 0x7fff + ((v.u >> 16) & 1);   // RNE
    return (short)(r >> 16);
}

#if __has_builtin(__builtin_amdgcn_exp2f)
#define EXP2(x) __builtin_amdgcn_exp2f(x)
#else
#define EXP2(x) __expf((x) * 0.6931471805599453f)
#endif

// v_cvt_pk_bf16_f32: low16 = bf16(a), high16 = bf16(b)
__device__ __forceinline__ unsigned cvt_pk_bf16(float a, float b) {
    unsigned r;
    asm("v_cvt_pk_bf16_f32 %0, %1, %2" : "=v"(r) : "v"(a), "v"(b));
    return r;
}

// async global->LDS, 16B per lane. LDS base must be wave-uniform.
__device__ __forceinline__ void gld16(const void* g, void* l) {
    __builtin_amdgcn_global_load_lds(
        (const __attribute__((address_space(1))) void*)g,
        (__attribute__((address_space(3))) void*)l, 16, 0, 0);
}

// ---------------------------------------------------------------------------
// fp32 -> bf16 conversion: X (4096x768) and the 4 weight matrices (768x768).
// ---------------------------------------------------------------------------
#define XV8   393216
#define WV8   73728
__global__ __launch_bounds__(256)
void cvt_kernel(const float* __restrict__ X, short* __restrict__ Xb,
                const float* __restrict__ W0, short* __restrict__ W0b,
                const float* __restrict__ W1, short* __restrict__ W1b,
                const float* __restrict__ W2, short* __restrict__ W2b,
                const float* __restrict__ W3, short* __restrict__ W3b)
{
    int gid = blockIdx.x * 256 + threadIdx.x;
    const float* src; short* dst; size_t off;
    if      (gid < XV8)            { src = X;  dst = Xb;  off = gid; }
    else if (gid < XV8 + WV8)      { src = W0; dst = W0b; off = gid - XV8; }
    else if (gid < XV8 + 2*WV8)    { src = W1; dst = W1b; off = gid - XV8 - WV8; }
    else if (gid < XV8 + 3*WV8)    { src = W2; dst = W2b; off = gid - XV8 - 2*WV8; }
    else if (gid < XV8 + 4*WV8)    { src = W3; dst = W3b; off = gid - XV8 - 3*WV8; }
    else return;
    off *= 8;
    float4 a = *(const float4*)(src + off);
    float4 b = *(const float4*)(src + off + 4);
    s8v o;
    o[0] = f2bf(a.x); o[1] = f2bf(a.y); o[2] = f2bf(a.z); o[3] = f2bf(a.w);
    o[4] = f2bf(b.x); o[5] = f2bf(b.y); o[6] = f2bf(b.z); o[7] = f2bf(b.w);
    *(s8v*)(dst + off) = o;
}

// ---------------------------------------------------------------------------
// MFMA GEMM, 128x128 tile, BK=32, 4 waves (2x2, 64x64 each).
// EPI 0: fused QKV -> bf16 [B,NH,S,HD], Q scaled by 0.125*log2(e).
// EPI 1: out-proj -> fp32 [4096,768] + bias + residual.
// ---------------------------------------------------------------------------
template<int EPI>
__global__ __launch_bounds__(256)
void gemm_mfma(const short* __restrict__ A,
               const short* __restrict__ Wq, const short* __restrict__ Wk,
               const short* __restrict__ Wv,
               const float* __restrict__ bq, const float* __restrict__ bk,
               const float* __restrict__ bv,
               short* __restrict__ Qo, short* __restrict__ Ko, short* __restrict__ Vo,
               const float* __restrict__ Xres, float* __restrict__ Fo)
{
    __shared__ __align__(16) short As[128*32];
    __shared__ __align__(16) short Bs[128*32];

    const int tid  = threadIdx.x;
    const int w    = tid >> 6;
    const int lane = tid & 63;
    const int g    = lane >> 4;
    const int r    = lane & 15;
    const int wr   = w >> 1;
    const int wc   = w & 1;
    const int m0   = blockIdx.y * 128;

    int n0;
    const short* Wb; const float* bias; short* outp; float scale;
    if (EPI == 0) {
        const int seg = blockIdx.x / 6;
        n0 = (blockIdx.x % 6) * 128;
        Wb   = seg == 0 ? Wq : seg == 1 ? Wk : Wv;
        bias = seg == 0 ? bq : seg == 1 ? bk : bv;
        outp = seg == 0 ? Qo : seg == 1 ? Ko : Vo;
        scale = seg == 0 ? (0.125f * L2E) : 1.0f;
    } else {
        n0 = blockIdx.x * 128;
        Wb = Wq; bias = bq; outp = nullptr; scale = 1.0f;
    }

    const int lrow = lane >> 2;
    const int lcol = (lane & 3) * 8;
    const short* Ag0 = A  + (size_t)(m0 + w*32 + lrow) * HH + lcol;
    const short* Bg0 = Wb + (size_t)(n0 + w*32 + lrow) * HH + lcol;
    short* Al0 = As + (w*32)      * 32;
    short* Al1 = As + (w*32 + 16) * 32;
    short* Bl0 = Bs + (w*32)      * 32;
    short* Bl1 = Bs + (w*32 + 16) * 32;

    f4v acc[4][4];
    #pragma unroll
    for (int i = 0; i < 4; i++)
        #pragma unroll
        for (int j = 0; j < 4; j++) acc[i][j] = (f4v){0.f,0.f,0.f,0.f};

    for (int kt = 0; kt < HH/32; ++kt) {
        const int k0 = kt * 32;
        gld16(Ag0 + k0,           Al0);
        gld16(Ag0 + k0 + 16*HH,   Al1);
        gld16(Bg0 + k0,           Bl0);
        gld16(Bg0 + k0 + 16*HH,   Bl1);
        __syncthreads();

        s8v af[4], bf[4];
        #pragma unroll
        for (int mi = 0; mi < 4; mi++)
            af[mi] = *(const s8v*)(As + (wr*64 + mi*16 + r)*32 + g*8);
        #pragma unroll
        for (int ni = 0; ni < 4; ni++)
            bf[ni] = *(const s8v*)(Bs + (wc*64 + ni*16 + r)*32 + g*8);
        __builtin_amdgcn_s_setprio(1);
        #pragma unroll
        for (int mi = 0; mi < 4; mi++)
            #pragma unroll
            for (int ni = 0; ni < 4; ni++)
                acc[mi][ni] = __builtin_amdgcn_mfma_f32_16x16x32_bf16(af[mi], bf[ni], acc[mi][ni], 0, 0, 0);
        __builtin_amdgcn_s_setprio(0);
        __syncthreads();
    }

    if (EPI == 0) {
        #pragma unroll
        for (int mi = 0; mi < 4; mi++) {
            #pragma unroll
            for (int j = 0; j < 4; j++) {
                const int m = m0 + wr*64 + mi*16 + 4*g + j;
                const int bb = m >> 11;
                const int s  = m & 2047;
                #pragma unroll
                for (int ni = 0; ni < 4; ni++) {
                    const int n = n0 + wc*64 + ni*16 + r;
                    const int h = n >> 6;
                    const int d = n & 63;
                    outp[((size_t)((bb*NHEADS + h)*SEQ) + s)*HDIM + d] =
                        f2bf((acc[mi][ni][j] + bias[n]) * scale);
                }
            }
        }
    } else {
        #pragma unroll
        for (int mi = 0; mi < 4; mi++) {
            #pragma unroll
            for (int j = 0; j < 4; j++) {
                const int m = m0 + wr*64 + mi*16 + 4*g + j;
                #pragma unroll
                for (int ni = 0; ni < 4; ni++) {
                    const int n = n0 + wc*64 + ni*16 + r;
                    Fo[(size_t)m*HH + n] = acc[mi][ni][j] + bias[n] + Xres[(size_t)m*HH + n];
                }
            }
        }
    }
}

// ---------------------------------------------------------------------------
// V [B,NH,S,HD] -> VT [B,NH,HD,S], 64x64 LDS tiles.
// ---------------------------------------------------------------------------
__global__ __launch_bounds__(256)
void vtrans_kernel(const short* __restrict__ V, short* __restrict__ VT)
{
    const int st = blockIdx.x;
    const int h  = blockIdx.y;
    const int b  = blockIdx.z;
    __shared__ short T[64][72];
    const int t = threadIdx.x;
    const short* src = V + ((size_t)(b*NHEADS + h)*SEQ + st*64) * HDIM;

    {
        const int sl = t >> 2;
        const int dq = (t & 3) * 16;
        s8v a = *(const s8v*)(src + sl*HDIM + dq);
        s8v c = *(const s8v*)(src + sl*HDIM + dq + 8);
        #pragma unroll
        for (int i = 0; i < 8; i++) { T[dq+i][sl] = a[i]; T[dq+8+i][sl] = c[i]; }
    }
    __syncthreads();
    {
        const int d  = t >> 2;
        const int sq = (t & 3) * 16;
        s8v o0 = *(const s8v*)&T[d][sq];
        s8v o1 = *(const s8v*)&T[d][sq+8];
        short* dst = VT + ((size_t)(b*NHEADS + h)*HDIM + d)*SEQ + st*64 + sq;
        *(s8v*)(dst)     = o0;
        *(s8v*)(dst + 8) = o1;
    }
}

// ---------------------------------------------------------------------------
// Flash attention, bf16 MFMA, exp2-space softmax, dbuf LDS (1 barrier/tile),
// defer-rescale (THR=8 in log2 space), setprio around MFMA.
// Q pre-scaled by 0.125*log2e. K: [B,NH,S,HD]. VT: [B,NH,HD,S]. CTX: bf16.
// ---------------------------------------------------------------------------
#define NT (SEQ/64)
__global__ __launch_bounds__(256)
void attn_mfma(const short* __restrict__ Q, const short* __restrict__ K,
               const short* __restrict__ VT, const float* __restrict__ mask,
               short* __restrict__ CTX)
{
    const int qt = blockIdx.x;
    const int h  = blockIdx.y;
    const int b  = blockIdx.z;
    const size_t hb = (size_t)(b * NHEADS + h);
    const short* Qg  = Q  + hb * SEQ * HDIM;
    const short* Kg  = K  + hb * SEQ * HDIM;
    const short* VTg = VT + hb * HDIM * SEQ;

    __shared__ __align__(16) char KsB[2][8192];
    __shared__ __align__(16) char VTsB[2][8192];
    __shared__ __align__(16) char PlsB[4][2048];

    const int tid  = threadIdx.x;
    const int w    = tid >> 6;
    const int lane = tid & 63;
    const int g    = lane >> 4;
    const int r    = lane & 15;
    const int q0   = qt * 64;

    const short* qrow = Qg + (size_t)(q0 + w*16 + r) * HDIM;
    const s8v qf0 = *(const s8v*)(qrow + 8*g);
    const s8v qf1 = *(const s8v*)(qrow + 8*g + 32);

    f4v acc[4];
    #pragma unroll
    for (int t = 0; t < 4; t++) acc[t] = (f4v){0.f, 0.f, 0.f, 0.f};
    float mrow[4] = {-1e30f, -1e30f, -1e30f, -1e30f};
    float lrow[4] = {0.f, 0.f, 0.f, 0.f};

    s8v kr0, kr1, vr0, vr1;
    const int sr0 = tid >> 3;
    const int sce = (tid & 7) * 8;
    const int scb = (tid & 7) * 16;

    #define LOADT(K0) do {                                                   \
        kr0 = *(const s8v*)(Kg  + (size_t)((K0) + sr0)      * HDIM + sce);   \
        kr1 = *(const s8v*)(Kg  + (size_t)((K0) + sr0 + 32) * HDIM + sce);   \
        vr0 = *(const s8v*)(VTg + (size_t)(sr0)      * SEQ + (K0) + sce);    \
        vr1 = *(const s8v*)(VTg + (size_t)(sr0 + 32) * SEQ + (K0) + sce);    \
    } while (0)

    #define STORET(BUF) do {                                                 \
        char* kd = KsB[BUF]; char* vd = VTsB[BUF];                           \
        *(s8v*)(kd + sr0*128      + (scb ^ ((sr0 & 7) << 4)))      = kr0;    \
        *(s8v*)(vd + sr0*128      + (scb ^ ((sr0 & 7) << 4)))      = vr0;    \
        *(s8v*)(kd + (sr0+32)*128 + (scb ^ (((sr0+32) & 7) << 4))) = kr1;    \
        *(s8v*)(vd + (sr0+32)*128 + (scb ^ (((sr0+32) & 7) << 4))) = vr1;    \
    } while (0)

    LOADT(0);
    STORET(0);
    LOADT(64);
    __syncthreads();

    for (int kt = 0; kt < NT; ++kt) {
        const int cur = kt & 1;
        const char* Kc = KsB[cur];
        const char* Vc = VTsB[cur];
        const int k0 = kt * 64;

        float madd[4];
        #pragma unroll
        for (int j = 0; j < 4; j++)
            madd[j] = (mask[b*SEQ + k0 + 16*j + r] - 1.0f) * (10000.0f * L2E);

        // ---- QK^T (scores already in log2 space via Q pre-scale) ----
        f4v sj[4];
        __builtin_amdgcn_s_setprio(1);
        #pragma unroll
        for (int j = 0; j < 4; j++) {
            const int krow = 16*j + r;
            const char* kb = Kc + krow * 128;
            const int sw = (krow & 7) << 4;
            s8v kf0 = *(const s8v*)(kb + ((16*g)      ^ sw));
            s8v kf1 = *(const s8v*)(kb + ((16*g + 64) ^ sw));
            f4v z = (f4v){0.f, 0.f, 0.f, 0.f};
            z = __builtin_amdgcn_mfma_f32_16x16x32_bf16(qf0, kf0, z, 0, 0, 0);
            z = __builtin_amdgcn_mfma_f32_16x16x32_bf16(qf1, kf1, z, 0, 0, 0);
            #pragma unroll
            for (int i = 0; i < 4; i++) z[i] += madd[j];
            sj[j] = z;
        }
        __builtin_amdgcn_s_setprio(0);

        // ---- stage next tile (DS writes + global prefetch overlap softmax) ----
        if (kt + 1 < NT) STORET(cur ^ 1);
        if (kt + 2 < NT) LOADT((kt + 2) * 64);

        // ---- online softmax in exp2 space, defer-rescale ----
        float rm[4];
        bool grow = false;
        #pragma unroll
        for (int i = 0; i < 4; i++) {
            float v = fmaxf(fmaxf(sj[0][i], sj[1][i]), fmaxf(sj[2][i], sj[3][i]));
            v = fmaxf(v, __shfl_xor(v, 1));
            v = fmaxf(v, __shfl_xor(v, 2));
            v = fmaxf(v, __shfl_xor(v, 4));
            v = fmaxf(v, __shfl_xor(v, 8));
            rm[i] = v;
            grow = grow || (v > mrow[i] + 8.0f);
        }
        const bool resc = __any(grow);
        float alpha[4];
        if (resc) {
            #pragma unroll
            for (int i = 0; i < 4; i++) {
                const float mn = fmaxf(mrow[i], rm[i]);
                alpha[i] = EXP2(mrow[i] - mn);
                mrow[i] = mn;
            }
        }
        #pragma unroll
        for (int j = 0; j < 4; j++)
            #pragma unroll
            for (int i = 0; i < 4; i++)
                sj[j][i] = EXP2(sj[j][i] - mrow[i]);
        #pragma unroll
        for (int i = 0; i < 4; i++) {
            float rs = (sj[0][i] + sj[1][i]) + (sj[2][i] + sj[3][i]);
            rs += __shfl_xor(rs, 1);
            rs += __shfl_xor(rs, 2);
            rs += __shfl_xor(rs, 4);
            rs += __shfl_xor(rs, 8);
            lrow[i] = resc ? (lrow[i] * alpha[i] + rs) : (lrow[i] + rs);
        }

        // ---- P -> bf16 (cvt_pk) -> per-wave LDS ----
        char* pb = PlsB[w];
        #pragma unroll
        for (int i = 0; i < 4; i++) {
            const int prow = 4*g + i;
            char* base = pb + prow * 128;
            const int sw = (prow & 7) << 4;
            unsigned p01 = cvt_pk_bf16(sj[0][i], sj[1][i]);
            unsigned p23 = cvt_pk_bf16(sj[2][i], sj[3][i]);
            *(short*)(base + (((16*0 + r) * 2) ^ sw)) = (short)(p01 & 0xffff);
            *(short*)(base + (((16*1 + r) * 2) ^ sw)) = (short)(p01 >> 16);
            *(short*)(base + (((16*2 + r) * 2) ^ sw)) = (short)(p23 & 0xffff);
            *(short*)(base + (((16*3 + r) * 2) ^ sw)) = (short)(p23 >> 16);
        }

        if (resc) {
            #pragma unroll
            for (int t = 0; t < 4; t++)
                #pragma unroll
                for (int i = 0; i < 4; i++)
                    acc[t][i] *= alpha[i];
        }

        // ---- ctx += P @ V ----
        __builtin_amdgcn_s_setprio(1);
        #pragma unroll
        for (int c = 0; c < 2; c++) {
            s8v pf = *(const s8v*)(pb + r*128 + ((16*g + 64*c) ^ ((r & 7) << 4)));
            #pragma unroll
            for (int t = 0; t < 4; t++) {
                const int vrow = 16*t + r;
                s8v vf = *(const s8v*)(Vc + vrow*128 + ((16*g + 64*c) ^ ((vrow & 7) << 4)));
                acc[t] = __builtin_amdgcn_mfma_f32_16x16x32_bf16(pf, vf, acc[t], 0, 0, 0);
            }
        }
        __builtin_amdgcn_s_setprio(0);

        __syncthreads();
    }

    #pragma unroll
    for (int i = 0; i < 4; i++) {
        const float invl = 1.0f / lrow[i];
        const size_t rowbase = ((size_t)(b*SEQ) + q0 + w*16 + 4*g + i) * HH + h*HDIM;
        #pragma unroll
        for (int t = 0; t < 4; t++)
            CTX[rowbase + 16*t + r] = f2bf(acc[t][i] * invl);
    }
    #undef LOADT
    #undef STORET
}

// ---------------------------------------------------------------------------
// In-place LayerNorm over rows of 768.
// ---------------------------------------------------------------------------
__global__ __launch_bounds__(256)
void ln_kernel(float* __restrict__ y, const float* __restrict__ gamma,
               const float* __restrict__ beta)
{
    const int row = blockIdx.x;
    float* p = y + (size_t)row * HH;
    const int tid = threadIdx.x;

    float v[3];
    float s = 0.f, ss = 0.f;
    #pragma unroll
    for (int i = 0; i < 3; i++) {
        float x = p[tid + i*256];
        v[i] = x;
        s += x;
        ss += x * x;
    }
    #pragma unroll
    for (int off = 32; off > 0; off >>= 1) {
        s  += __shfl_down(s,  off);
        ss += __shfl_down(ss, off);
    }
    __shared__ float sbuf[4], ssbuf[4];
    __shared__ float mu_s, rstd_s;
    const int wave = tid >> 6;
    if ((tid & 63) == 0) { sbuf[wave] = s; ssbuf[wave] = ss; }
    __syncthreads();
    if (tid == 0) {
        float S  = sbuf[0] + sbuf[1] + sbuf[2] + sbuf[3];
        float SS = ssbuf[0] + ssbuf[1] + ssbuf[2] + ssbuf[3];
        float mu = S * (1.0f / HH);
        float var = SS * (1.0f / HH) - mu * mu;
        mu_s = mu;
        rstd_s = rsqrtf(var + 1e-5f);
    }
    __syncthreads();
    const float mu = mu_s, rstd = rstd_s;
    #pragma unroll
    for (int i = 0; i < 3; i++) {
        const int c = tid + i*256;
        p[c] = (v[i] - mu) * rstd * gamma[c] + beta[c];
    }
}

// ---------------------------------------------------------------------------
extern "C" void kernel_launch(void* const* d_in, const int* in_sizes, int n_in,
                              void* d_out, int out_size, void* d_ws, size_t ws_size,
                              hipStream_t stream)
{
    const float* x     = (const float*)d_in[0];
    const float* mask  = (const float*)d_in[1];
    const float* Wq    = (const float*)d_in[2];
    const float* bq    = (const float*)d_in[3];
    const float* Wk    = (const float*)d_in[4];
    const float* bk    = (const float*)d_in[5];
    const float* Wv    = (const float*)d_in[6];
    const float* bv    = (const float*)d_in[7];
    const float* Wo    = (const float*)d_in[8];
    const float* bo    = (const float*)d_in[9];
    const float* gamma = (const float*)d_in[10];
    const float* beta  = (const float*)d_in[11];

    const size_t PER = (size_t)NB * NHEADS * SEQ * HDIM;
    const size_t WSZ = (size_t)HH * HH;
    short* wsS  = (short*)d_ws;
    short* Xb   = wsS;
    short* VTb  = wsS;
    short* Wqb  = wsS + PER;
    short* Wkb  = Wqb + WSZ;
    short* Wvb  = Wkb + WSZ;
    short* Wob  = Wvb + WSZ;
    short* Qb   = Wob + WSZ;
    short* Kb   = Qb + PER;
    short* Vb   = Kb + PER;
    short* CTXb = Vb;
    float* out  = (float*)d_out;

    cvt_kernel<<<2688, 256, 0, stream>>>(x, Xb, Wq, Wqb, Wk, Wkb, Wv, Wvb, Wo, Wob);

    gemm_mfma<0><<<dim3(18, 32), 256, 0, stream>>>(
        Xb, Wqb, Wkb, Wvb, bq, bk, bv, Qb, Kb, Vb, nullptr, nullptr);

    vtrans_kernel<<<dim3(SEQ/64, NHEADS, NB), 256, 0, stream>>>(Vb, VTb);

    attn_mfma<<<dim3(SEQ/64, NHEADS, NB), 256, 0, stream>>>(Qb, Kb, VTb, mask, CTXb);

    gemm_mfma<1><<<dim3(6, 32), 256, 0, stream>>>(
        CTXb, Wob, nullptr, nullptr, bo, nullptr, nullptr,
        nullptr, nullptr, nullptr, x, out);

    ln_kernel<<<NB*SEQ, 256, 0, stream>>>(out, gamma, beta);
}